// Round 1
// baseline (924.280 us; speedup 1.0000x reference)
//
#include <hip/hip_runtime.h>
#include <hip/hip_bf16.h>
#include <math.h>

typedef __hip_bfloat16 bf16;
typedef __attribute__((ext_vector_type(8))) short short8;
typedef __attribute__((ext_vector_type(4))) float floatx4;

#define NTOK 147456
#define IMG 384

__device__ __forceinline__ int gather_row(int m) {
    int gw = m >> 6, t = m & 63;
    int wr = gw / 48, wc = gw - wr * 48;
    int hh = wr * 8 + (t >> 3);
    int ww = wc * 8 + (t & 7);
    int oh = hh + 4; if (oh >= IMG) oh -= IMG;
    int ow = ww + 4; if (ow >= IMG) ow -= IMG;
    return oh * IMG + ow;
}

__device__ __forceinline__ unsigned short f2bu(float f) {
    unsigned u = __float_as_uint(f);
    unsigned r = (u + 0x7fffu + ((u >> 16) & 1u)) >> 16;   // RNE
    return (unsigned short)r;
}
__device__ __forceinline__ float bu2f(unsigned short u) {
    return __uint_as_float(((unsigned)u) << 16);
}

// fast exact-GELU: 0.5*x*(1+erf(x/sqrt2)); erf via A&S 7.1.26, |err|<1.5e-7
// (bf16 output rounding is ~3e-3 relative, so this is exact for our purposes)
__device__ __forceinline__ float gelu_fast(float x) {
    const float z = fabsf(x) * 0.70710678118654752f;
    const float t = __builtin_amdgcn_rcpf(fmaf(0.3275911f, z, 1.0f));
    float p = fmaf(1.061405429f, t, -1.453152027f);
    p = fmaf(p, t, 1.421413741f);
    p = fmaf(p, t, -0.284496736f);
    p = fmaf(p, t, 0.254829592f);
    p *= t;
    const float e = __expf(-z * z);
    float erfv = fmaf(-p, e, 1.0f);
    erfv = (x < 0.0f) ? -erfv : erfv;
    return 0.5f * x * (1.0f + erfv);
}

// ---------------- prep kernels ----------------

// hidden fp32 -> bf16 A-frag-packed, gathered window order: [mtG][kg24][m16][8]
__global__ __launch_bounds__(256)
void conv_pack(const float* __restrict__ hidden, bf16* __restrict__ Apk)
{
    const int cid = blockIdx.x * 256 + threadIdx.x;    // < 9216*24*16
    const int mtG = cid / 384;
    const int rest = cid - mtG * 384;
    const int kg = rest >> 4, mm = rest & 15;
    const int tok = mtG * 16 + mm;
    const float* p = hidden + (size_t)gather_row(tok) * 192 + kg * 8;
    const float4 a = *(const float4*)p;
    const float4 b = *(const float4*)(p + 4);
    short8 o;
    o[0] = (short)f2bu(a.x); o[1] = (short)f2bu(a.y);
    o[2] = (short)f2bu(a.z); o[3] = (short)f2bu(a.w);
    o[4] = (short)f2bu(b.x); o[5] = (short)f2bu(b.y);
    o[6] = (short)f2bu(b.z); o[7] = (short)f2bu(b.w);
    *(short8*)(Apk + (size_t)cid * 8) = o;
}

// W fp32 [K][N] row-major -> bf16 B-frag-packed [ntG][kg][n16][8]
__global__ __launch_bounds__(256)
void pack_w(const float* __restrict__ W, bf16* __restrict__ out, int K, int N)
{
    const int cid = blockIdx.x * 256 + threadIdx.x;
    const int KG = K >> 3;
    const int total = (N >> 4) * KG * 16;
    if (cid >= total) return;
    const int n = cid & 15;
    const int kg = (cid >> 4) % KG;
    const int ntG = (cid >> 4) / KG;
    short8 o;
#pragma unroll
    for (int j = 0; j < 8; ++j)
        o[j] = (short)f2bu(W[(size_t)(kg * 8 + j) * N + ntG * 16 + n]);
    *(short8*)(out + (size_t)cid * 8) = o;
}

__global__ __launch_bounds__(256)
void fuse_bias(const float* __restrict__ qb, const float* __restrict__ vb,
               float* __restrict__ out)
{
    const int t = blockIdx.x * 256 + threadIdx.x;
    if (t >= 576) return;
    out[t] = (t < 192) ? qb[t] : ((t < 384) ? 0.0f : vb[t - 384]);
}

// ---------------- MFMA GEMM ----------------
#define EPI_NONE 0
#define EPI_GELU 1

// A-fragments live in registers (packed layout == fragment layout, so the
// per-wave load is a coalesced direct global read; no sA staging, no sA
// barriers). LDS = sB only (24 KB) -> 4 blocks/CU for K=192, 3 for K=384.
template<int KDIM, bool PACK_OUT, int EPI, int KGOUT, int MW>
__global__ __launch_bounds__(256, MW)
void gemm_mfma(const bf16* __restrict__ Apk, const bf16* __restrict__ Bpk,
               const float* __restrict__ bias, bf16* __restrict__ C, int N)
{
    constexpr int KG = KDIM / 8;     // k-groups of 8
    constexpr int KT = KDIM / 32;    // A-frags per 16-row tile
    constexpr int KC = KDIM / 192;   // 192-wide K chunks (B staging granularity)
    __shared__ __align__(16) char sB[4 * 24 * 256];
    const int tid = threadIdx.x;
    const int wave = tid >> 6, lane = tid & 63;
    const int bm = blockIdx.x * 128;
    const int NPo = N / 64;
    const char* Bsrc = (const char*)Bpk;

    // ---- A-frags -> registers, once per block ----
    short8 areg[2][KT];
    {
        const char* Asrc = (const char*)Apk;
#pragma unroll
        for (int x = 0; x < 2; ++x) {
            const size_t rowb = (size_t)((bm >> 4) + wave * 2 + x) * KG * 256;
#pragma unroll
            for (int kt = 0; kt < KT; ++kt)
                areg[x][kt] = *(const short8*)(Asrc + rowb + (size_t)kt * 1024 + lane * 16);
        }
    }

    for (int npo = 0; npo < NPo; ++npo) {
        floatx4 acc[8];
#pragma unroll
        for (int f = 0; f < 8; ++f)
            acc[f] = (floatx4){0.f, 0.f, 0.f, 0.f};

        for (int kc = 0; kc < KC; ++kc) {
            __syncthreads();                      // protect sB (prev mfma reads / epilogue)
#pragma unroll
            for (int i = 0; i < 6; ++i) {
                const int cid = tid + (i << 8);
                const int nt = cid / 384, off = cid - nt * 384;
                const size_t src = ((size_t)(npo * 4 + nt) * KG + kc * 24) * 256 + (size_t)off * 16;
                *(short8*)(sB + nt * 6144 + off * 16) = *(const short8*)(Bsrc + src);
            }
            __syncthreads();
#pragma unroll
            for (int kt6 = 0; kt6 < 6; ++kt6) {
                const int kt = kc * 6 + kt6;
                const short8 a0 = areg[0][kt];
                const short8 a1 = areg[1][kt];
#pragma unroll
                for (int nt = 0; nt < 4; ++nt) {
                    const short8 b = *(const short8*)(sB + nt * 6144 + kt6 * 1024 + lane * 16);
                    acc[nt]     = __builtin_amdgcn_mfma_f32_16x16x32_bf16(a0, b, acc[nt],     0, 0, 0);
                    acc[4 + nt] = __builtin_amdgcn_mfma_f32_16x16x32_bf16(a1, b, acc[4 + nt], 0, 0, 0);
                }
            }
        }

        // ---- epilogue: bias (+gelu), bf16, LDS transpose, coalesced store ----
        __syncthreads();
        char* wb = sB + wave * 4608;
#pragma unroll
        for (int m2 = 0; m2 < 2; ++m2) {
#pragma unroll
            for (int nt = 0; nt < 4; ++nt) {
                const floatx4 v = acc[m2 * 4 + nt];
                const int c = nt * 16 + (lane & 15);
                const float bval = bias ? bias[npo * 64 + c] : 0.0f;
#pragma unroll
                for (int i = 0; i < 4; ++i) {
                    float f = v[i] + bval;
                    if (EPI == EPI_GELU)
                        f = gelu_fast(f);
                    const int r = m2 * 16 + (lane >> 4) * 4 + i;
                    *(unsigned short*)(wb + (r * 72 + c) * 2) = f2bu(f);
                }
            }
        }
        __syncthreads();
        const int m = lane >> 1, coff = (lane & 1) * 32;
        const int grow = bm + wave * 32 + m;
#pragma unroll
        for (int i = 0; i < 4; ++i) {
            const short8 row = *(const short8*)(wb + (m * 72 + coff + i * 8) * 2);
            const int gcol = npo * 64 + coff + i * 8;
            bf16* dst;
            if (PACK_OUT)
                dst = C + ((size_t)((grow >> 4) * KGOUT + (gcol >> 3)) * 16 + (grow & 15)) * 8;
            else
                dst = C + (size_t)grow * N + gcol;
            *(short8*)dst = row;
        }
    }
}

// ---------------- CPB MLP + RPB ----------------

__device__ __forceinline__ float cpb_coord(int i) {
    float a = (float)(i - 7) * (8.0f / 7.0f);
    float s = (a > 0.f) ? 1.f : ((a < 0.f) ? -1.f : 0.f);
    return s * log2f(fabsf(a) + 1.0f) * (1.0f / 3.0f);
}

__global__ __launch_bounds__(512)
void cpb_mlp(const float* __restrict__ w1, const float* __restrict__ b1,
             const float* __restrict__ w2, float* __restrict__ tab)
{
    const int r = blockIdx.x;
    const int t = threadIdx.x;
    const float x0 = cpb_coord(r / 15);
    const float x1 = cpb_coord(r % 15);
    const float hgt = fmaxf(x0 * w1[t] + x1 * w1[512 + t] + b1[t], 0.0f);
    __shared__ float red[512];
    for (int n = 0; n < 6; ++n) {
        red[t] = hgt * w2[t * 6 + n];
        __syncthreads();
        for (int s = 256; s > 0; s >>= 1) {
            if (t < s) red[t] += red[t + s];
            __syncthreads();
        }
        if (t == 0) tab[r * 6 + n] = red[0];
        __syncthreads();
    }
}

__global__ __launch_bounds__(256)
void rpb_expand(const float* __restrict__ tab, float* __restrict__ rpb)
{
    const int idx = blockIdx.x * 256 + threadIdx.x;
    if (idx >= 6 * 4096) return;
    const int h = idx >> 12;
    const int t = (idx >> 6) & 63;
    const int j = idx & 63;
    const int pr = t >> 3, pc = t & 7, qr = j >> 3, qc = j & 7;
    const int ridx = (pr - qr + 7) * 15 + (pc - qc + 7);
    const float v = tab[ridx * 6 + h];
    rpb[idx] = 16.0f / (1.0f + expf(-v));
}

// ---------------- MFMA attention ----------------
// one wave per (window, head); 4 waves/block; all LDS wave-private (no barriers).
__global__ __launch_bounds__(256, 2)
void attn_mfma(const bf16* __restrict__ QKV, const float* __restrict__ rpb,
               const float* __restrict__ logit_scale, bf16* __restrict__ Ctx)
{
    __shared__ __align__(16) char lds[4][9216];
    const int wave = threadIdx.x >> 6, lane = threadIdx.x & 63;
    const int l15 = lane & 15, quad = lane >> 4;
    const int wh = blockIdx.x * 4 + wave;
    const int w = wh / 6, h = wh - w * 6;
    char* Pb = lds[wave];            // 64 rows x 36 bf16 (P halves, then ctx)
    char* Vt = lds[wave] + 4608;     // 32 rows x 72 bf16 (V transposed)

    const bf16* wbase = QKV + (size_t)w * 64 * 576;

    // ---- stage V^T: lane = token, writes its column (2 lanes/bank: free) ----
    {
        const bf16* vp = wbase + (size_t)lane * 576 + 384 + h * 32;
        const short8 v0 = *(const short8*)(vp);
        const short8 v1 = *(const short8*)(vp + 8);
        const short8 v2 = *(const short8*)(vp + 16);
        const short8 v3 = *(const short8*)(vp + 24);
#pragma unroll
        for (int j = 0; j < 8; ++j) {
            *(short*)(Vt + ((j     ) * 72 + lane) * 2) = v0[j];
            *(short*)(Vt + ((j +  8) * 72 + lane) * 2) = v1[j];
            *(short*)(Vt + ((j + 16) * 72 + lane) * 2) = v2[j];
            *(short*)(Vt + ((j + 24) * 72 + lane) * 2) = v3[j];
        }
    }

    // ---- region ids (mask only matters on last window row/col) ----
    const int wr = w / 48, wc = w - wr * 48;
    const bool edge = (wr == 47) || (wc == 47);
    int rid_j[4];
    if (edge) {
#pragma unroll
        for (int jt = 0; jt < 4; ++jt) {
            const int t = jt * 16 + l15;
            const int rr = (wr == 47) ? (((t >> 3) < 4) ? 1 : 2) : 0;
            const int rc = (wc == 47) ? (((t & 7) < 4) ? 1 : 2) : 0;
            rid_j[jt] = rr * 3 + rc;
        }
    }

    // ---- K B-frags, cosine-normalized ----
    short8 bfrag[4];
#pragma unroll
    for (int jt = 0; jt < 4; ++jt) {
        const short8 raw = *(const short8*)(wbase + (size_t)(jt * 16 + l15) * 576 + 192 + h * 32 + quad * 8);
        float f[8]; float ss = 0.f;
#pragma unroll
        for (int j = 0; j < 8; ++j) { f[j] = bu2f((unsigned short)raw[j]); ss += f[j] * f[j]; }
        ss += __shfl_xor(ss, 16); ss += __shfl_xor(ss, 32);
        const float rn = 1.0f / fmaxf(sqrtf(ss), 1e-12f);
        short8 o;
#pragma unroll
        for (int j = 0; j < 8; ++j) o[j] = (short)f2bu(f[j] * rn);
        bfrag[jt] = o;
    }

    // ---- S = Qn Kn^T ----
    floatx4 acc[4][4];
#pragma unroll
    for (int it = 0; it < 4; ++it)
#pragma unroll
        for (int jt = 0; jt < 4; ++jt)
            acc[it][jt] = (floatx4){0.f, 0.f, 0.f, 0.f};
#pragma unroll
    for (int it = 0; it < 4; ++it) {
        const short8 raw = *(const short8*)(wbase + (size_t)(it * 16 + l15) * 576 + h * 32 + quad * 8);
        float f[8]; float ss = 0.f;
#pragma unroll
        for (int j = 0; j < 8; ++j) { f[j] = bu2f((unsigned short)raw[j]); ss += f[j] * f[j]; }
        ss += __shfl_xor(ss, 16); ss += __shfl_xor(ss, 32);
        const float rn = 1.0f / fmaxf(sqrtf(ss), 1e-12f);
        short8 afr;
#pragma unroll
        for (int j = 0; j < 8; ++j) afr[j] = (short)f2bu(f[j] * rn);
#pragma unroll
        for (int jt = 0; jt < 4; ++jt)
            acc[it][jt] = __builtin_amdgcn_mfma_f32_16x16x32_bf16(afr, bfrag[jt], acc[it][jt], 0, 0, 0);
    }

    const float scale = __expf(fminf(logit_scale[h], 4.6051701859880914f));
    const float* rpbh = rpb + h * 4096;

    // ---- scale + bias + mask (C-layout: row = it*16+quad*4+r, col = jt*16+l15) ----
#pragma unroll
    for (int it = 0; it < 4; ++it) {
#pragma unroll
        for (int r = 0; r < 4; ++r) {
            const int i = it * 16 + quad * 4 + r;
            int rid_i = 0;
            if (edge) {
                const int rr = (wr == 47) ? (((i >> 3) < 4) ? 1 : 2) : 0;
                const int rc = (wc == 47) ? (((i & 7) < 4) ? 1 : 2) : 0;
                rid_i = rr * 3 + rc;
            }
#pragma unroll
            for (int jt = 0; jt < 4; ++jt) {
                float v = acc[it][jt][r] * scale + rpbh[i * 64 + jt * 16 + l15];
                if (edge && rid_i != rid_j[jt]) v -= 200.0f;   // mask added twice in ref
                acc[it][jt][r] = v;
            }
        }
    }

    // ---- softmax per row; keep 1/sum for post-PV scaling ----
    float inv[4][4];
#pragma unroll
    for (int it = 0; it < 4; ++it) {
#pragma unroll
        for (int r = 0; r < 4; ++r) {
            float m = fmaxf(fmaxf(acc[it][0][r], acc[it][1][r]),
                            fmaxf(acc[it][2][r], acc[it][3][r]));
            m = fmaxf(m, __shfl_xor(m, 1)); m = fmaxf(m, __shfl_xor(m, 2));
            m = fmaxf(m, __shfl_xor(m, 4)); m = fmaxf(m, __shfl_xor(m, 8));
            float s = 0.f;
#pragma unroll
            for (int jt = 0; jt < 4; ++jt) {
                const float e = __expf(acc[it][jt][r] - m);
                acc[it][jt][r] = e; s += e;
            }
            s += __shfl_xor(s, 1); s += __shfl_xor(s, 2);
            s += __shfl_xor(s, 4); s += __shfl_xor(s, 8);
            inv[it][r] = 1.0f / s;
        }
    }

    // ---- ctx = P V via LDS round-trip in two 32-key halves ----
    floatx4 ctx[4][2];
#pragma unroll
    for (int it = 0; it < 4; ++it)
#pragma unroll
        for (int dt = 0; dt < 2; ++dt)
            ctx[it][dt] = (floatx4){0.f, 0.f, 0.f, 0.f};

#pragma unroll
    for (int ks = 0; ks < 2; ++ks) {
#pragma unroll
        for (int it = 0; it < 4; ++it)
#pragma unroll
            for (int jl = 0; jl < 2; ++jl)
#pragma unroll
                for (int r = 0; r < 4; ++r) {
                    const int i = it * 16 + quad * 4 + r;
                    *(short*)(Pb + (i * 36 + jl * 16 + l15) * 2) =
                        (short)f2bu(acc[it][ks * 2 + jl][r]);
                }
#pragma unroll
        for (int it = 0; it < 4; ++it) {
            const short8 pf = *(const short8*)(Pb + ((it * 16 + l15) * 36 + quad * 8) * 2);
#pragma unroll
            for (int dt = 0; dt < 2; ++dt) {
                const short8 vf = *(const short8*)(Vt + ((dt * 16 + l15) * 72 + ks * 32 + quad * 8) * 2);
                ctx[it][dt] = __builtin_amdgcn_mfma_f32_16x16x32_bf16(pf, vf, ctx[it][dt], 0, 0, 0);
            }
        }
    }

    // ---- ctx/sum -> LDS (reuse Pb; same-wave order keeps it race-free) ----
#pragma unroll
    for (int it = 0; it < 4; ++it)
#pragma unroll
        for (int dt = 0; dt < 2; ++dt)
#pragma unroll
            for (int r = 0; r < 4; ++r) {
                const int i = it * 16 + quad * 4 + r;
                *(short*)(Pb + (i * 36 + dt * 16 + l15) * 2) =
                    (short)f2bu(ctx[it][dt][r] * inv[it][r]);
            }

    // ---- packed-A-layout store for proj GEMM ----
    const int tok = w * 64 + lane;
    const size_t obase = ((size_t)(tok >> 4) * 24 + h * 4) * 128 + (size_t)(tok & 15) * 8;
#pragma unroll
    for (int c = 0; c < 4; ++c) {
        const short8 row = *(const short8*)(Pb + (lane * 36 + c * 8) * 2);
        *(short8*)(Ctx + obase + (size_t)c * 128) = row;
    }
}

// ---------------- LN kernels ----------------

__global__ __launch_bounds__(256)
void ln_h(const bf16* __restrict__ X, const float* __restrict__ hidden,
          const float* __restrict__ g, const float* __restrict__ b,
          bf16* __restrict__ Hres, bf16* __restrict__ Hpk)
{
    const int lane = threadIdx.x & 63;
    const int wv = threadIdx.x >> 6;
    const int tok = blockIdx.x * 4 + wv;
    const int grow = gather_row(tok);
    __shared__ float rows[4][192];
    const bf16* xr = X + (size_t)tok * 192;
    const float x0 = bu2f(*(const unsigned short*)(xr + lane));
    const float x1 = bu2f(*(const unsigned short*)(xr + lane + 64));
    const float x2 = bu2f(*(const unsigned short*)(xr + lane + 128));
    float s = x0 + x1 + x2;
#pragma unroll
    for (int o = 32; o > 0; o >>= 1) s += __shfl_xor(s, o);
    const float mean = s * (1.0f / 192.0f);
    const float d0 = x0 - mean, d1 = x1 - mean, d2 = x2 - mean;
    float vsum = d0 * d0 + d1 * d1 + d2 * d2;
#pragma unroll
    for (int o = 32; o > 0; o >>= 1) vsum += __shfl_xor(vsum, o);
    const float rstd = rsqrtf(vsum * (1.0f / 192.0f) + 1e-5f);
    const float* hr = hidden + (size_t)grow * 192;
    const float h0 = hr[lane]       + d0 * rstd * g[lane]       + b[lane];
    const float h1 = hr[lane + 64]  + d1 * rstd * g[lane + 64]  + b[lane + 64];
    const float h2 = hr[lane + 128] + d2 * rstd * g[lane + 128] + b[lane + 128];
    bf16* hres = Hres + (size_t)tok * 192;
    *(unsigned short*)(hres + lane)       = f2bu(h0);
    *(unsigned short*)(hres + lane + 64)  = f2bu(h1);
    *(unsigned short*)(hres + lane + 128) = f2bu(h2);
    rows[wv][lane] = h0; rows[wv][lane + 64] = h1; rows[wv][lane + 128] = h2;
    __syncthreads();
    if (lane < 24) {
        short8 o;
#pragma unroll
        for (int j = 0; j < 8; ++j) o[j] = (short)f2bu(rows[wv][lane * 8 + j]);
        const int mtG = tok >> 4, mm = tok & 15;
        *(short8*)(Hpk + ((size_t)(mtG * 24 + lane) * 16 + mm) * 8) = o;
    }
}

__global__ __launch_bounds__(256)
void ln_out(const bf16* __restrict__ Y, const bf16* __restrict__ Hres,
            const float* __restrict__ g, const float* __restrict__ b,
            float* __restrict__ Out)
{
    const int lane = threadIdx.x & 63;
    const int tok = blockIdx.x * 4 + (threadIdx.x >> 6);
    const int grow = gather_row(tok);
    const bf16* yr = Y + (size_t)tok * 192;
    const float x0 = bu2f(*(const unsigned short*)(yr + lane));
    const float x1 = bu2f(*(const unsigned short*)(yr + lane + 64));
    const float x2 = bu2f(*(const unsigned short*)(yr + lane + 128));
    float s = x0 + x1 + x2;
#pragma unroll
    for (int o = 32; o > 0; o >>= 1) s += __shfl_xor(s, o);
    const float mean = s * (1.0f / 192.0f);
    const float d0 = x0 - mean, d1 = x1 - mean, d2 = x2 - mean;
    float vsum = d0 * d0 + d1 * d1 + d2 * d2;
#pragma unroll
    for (int o = 32; o > 0; o >>= 1) vsum += __shfl_xor(vsum, o);
    const float rstd = rsqrtf(vsum * (1.0f / 192.0f) + 1e-5f);
    const bf16* hr = Hres + (size_t)tok * 192;
    float* op = Out + (size_t)grow * 192;
    op[lane]       = bu2f(*(const unsigned short*)(hr + lane))       + d0 * rstd * g[lane]       + b[lane];
    op[lane + 64]  = bu2f(*(const unsigned short*)(hr + lane + 64))  + d1 * rstd * g[lane + 64]  + b[lane + 64];
    op[lane + 128] = bu2f(*(const unsigned short*)(hr + lane + 128)) + d2 * rstd * g[lane + 128] + b[lane + 128];
}

// ---------------- launch ----------------

extern "C" void kernel_launch(void* const* d_in, const int* in_sizes, int n_in,
                              void* d_out, int out_size, void* d_ws, size_t ws_size,
                              hipStream_t stream)
{
    const float* hidden = (const float*)d_in[0];
    const float* q_w = (const float*)d_in[1];
    const float* q_b = (const float*)d_in[2];
    const float* k_w = (const float*)d_in[3];
    const float* v_w = (const float*)d_in[4];
    const float* v_b = (const float*)d_in[5];
    const float* logit_scale = (const float*)d_in[6];
    const float* cpb_w1 = (const float*)d_in[7];
    const float* cpb_b1 = (const float*)d_in[8];
    const float* cpb_w2 = (const float*)d_in[9];
    const float* proj_w = (const float*)d_in[10];
    const float* proj_b = (const float*)d_in[11];
    const float* ln1_g = (const float*)d_in[12];
    const float* ln1_b = (const float*)d_in[13];
    const float* fc1_w = (const float*)d_in[14];
    const float* fc1_b = (const float*)d_in[15];
    const float* fc2_w = (const float*)d_in[16];
    const float* fc2_b = (const float*)d_in[17];
    const float* ln2_g = (const float*)d_in[18];
    const float* ln2_b = (const float*)d_in[19];

    char* ws = (char*)d_ws;
    bf16*  APK   = (bf16*)(ws + 0);
    float* RPB   = (float*)(ws + 0);
    bf16*  PROJW = (bf16*)(ws + (1 << 20));
    bf16*  MID   = (bf16*)(ws + 0);
    bf16*  CTX   = (bf16*)(ws + 56623104);
    bf16*  QKVW  = (bf16*)(ws + 56623104);
    float* QKVB  = (float*)(ws + 56844288);
    float* TAB   = (float*)(ws + 56846592);
    bf16*  QKV   = (bf16*)(ws + 113246208);
    bf16*  HRES  = (bf16*)(ws + 113246208);
    bf16*  HPK   = (bf16*)(ws + 169869312);
    bf16*  Y     = (bf16*)(ws + 226492416);
    bf16*  X     = (bf16*)(ws + 283115520);
    bf16*  FC1W  = (bf16*)(ws + 283115520);
    bf16*  FC2W  = (bf16*)(ws + 283262976);
    float* OUT   = (float*)d_out;

    cpb_mlp<<<225, 512, 0, stream>>>(cpb_w1, cpb_b1, cpb_w2, TAB);
    fuse_bias<<<3, 256, 0, stream>>>(q_b, v_b, QKVB);
    pack_w<<<18, 256, 0, stream>>>(q_w, QKVW,                 192, 192);
    pack_w<<<18, 256, 0, stream>>>(k_w, QKVW + 12 * 24 * 128, 192, 192);
    pack_w<<<18, 256, 0, stream>>>(v_w, QKVW + 24 * 24 * 128, 192, 192);
    conv_pack<<<13824, 256, 0, stream>>>(hidden, APK);

    gemm_mfma<192, false, EPI_NONE, 1, 4><<<1152, 256, 0, stream>>>(APK, QKVW, QKVB, QKV, 576);

    rpb_expand<<<96, 256, 0, stream>>>(TAB, RPB);
    pack_w<<<18, 256, 0, stream>>>(proj_w, PROJW, 192, 192);

    attn_mfma<<<3456, 256, 0, stream>>>(QKV, RPB, logit_scale, CTX);

    gemm_mfma<192, false, EPI_NONE, 1, 4><<<1152, 256, 0, stream>>>(CTX, PROJW, proj_b, X, 192);

    ln_h<<<NTOK / 4, 256, 0, stream>>>(X, hidden, ln1_g, ln1_b, HRES, HPK);

    pack_w<<<36, 256, 0, stream>>>(fc1_w, FC1W, 192, 384);
    pack_w<<<36, 256, 0, stream>>>(fc2_w, FC2W, 384, 192);

    gemm_mfma<192, true, EPI_GELU, 48, 4><<<1152, 256, 0, stream>>>(HPK, FC1W, fc1_b, MID, 384);
    gemm_mfma<384, false, EPI_NONE, 1, 3><<<1152, 256, 0, stream>>>(MID, FC2W, fc2_b, Y, 192);

    ln_out<<<NTOK / 4, 256, 0, stream>>>(Y, HRES, ln2_g, ln2_b, OUT);
}

// Round 2
// 652.679 us; speedup vs baseline: 1.4161x; 1.4161x over previous
//
#include <hip/hip_runtime.h>
#include <hip/hip_bf16.h>
#include <math.h>

typedef __hip_bfloat16 bf16;
typedef __attribute__((ext_vector_type(8))) short short8;
typedef __attribute__((ext_vector_type(4))) float floatx4;
typedef unsigned int u32;

#define NTOK 147456
#define IMG 384

__device__ __forceinline__ int gather_row(int m) {
    int gw = m >> 6, t = m & 63;
    int wr = gw / 48, wc = gw - wr * 48;
    int hh = wr * 8 + (t >> 3);
    int ww = wc * 8 + (t & 7);
    int oh = hh + 4; if (oh >= IMG) oh -= IMG;
    int ow = ww + 4; if (ow >= IMG) ow -= IMG;
    return oh * IMG + ow;
}

__device__ __forceinline__ unsigned short f2bu(float f) {
    unsigned u = __float_as_uint(f);
    unsigned r = (u + 0x7fffu + ((u >> 16) & 1u)) >> 16;   // RNE
    return (unsigned short)r;
}
__device__ __forceinline__ float bu2f(unsigned short u) {
    return __uint_as_float(((unsigned)u) << 16);
}

// fast exact-GELU: 0.5*x*(1+erf(x/sqrt2)); erf via A&S 7.1.26, |err|<1.5e-7
__device__ __forceinline__ float gelu_fast(float x) {
    const float z = fabsf(x) * 0.70710678118654752f;
    const float t = __builtin_amdgcn_rcpf(fmaf(0.3275911f, z, 1.0f));
    float p = fmaf(1.061405429f, t, -1.453152027f);
    p = fmaf(p, t, 1.421413741f);
    p = fmaf(p, t, -0.284496736f);
    p = fmaf(p, t, 0.254829592f);
    p *= t;
    const float e = __expf(-z * z);
    float erfv = fmaf(-p, e, 1.0f);
    erfv = (x < 0.0f) ? -erfv : erfv;
    return 0.5f * x * (1.0f + erfv);
}

// async global -> LDS, 16 B per lane; lds must be wave-uniform base (HW adds lane*16)
__device__ __forceinline__ void async_copy16(void* lds, const void* g) {
    __builtin_amdgcn_global_load_lds(
        (const __attribute__((address_space(1))) u32*)g,
        (__attribute__((address_space(3))) u32*)lds,
        16, 0, 0);
}

// ---------------- prep kernels ----------------

// hidden fp32 -> bf16 A-frag-packed, gathered window order: [mtG][kg24][m16][8]
__global__ __launch_bounds__(256)
void conv_pack(const float* __restrict__ hidden, bf16* __restrict__ Apk)
{
    const int cid = blockIdx.x * 256 + threadIdx.x;    // < 9216*24*16
    const int mtG = cid / 384;
    const int rest = cid - mtG * 384;
    const int kg = rest >> 4, mm = rest & 15;
    const int tok = mtG * 16 + mm;
    const float* p = hidden + (size_t)gather_row(tok) * 192 + kg * 8;
    const float4 a = *(const float4*)p;
    const float4 b = *(const float4*)(p + 4);
    short8 o;
    o[0] = (short)f2bu(a.x); o[1] = (short)f2bu(a.y);
    o[2] = (short)f2bu(a.z); o[3] = (short)f2bu(a.w);
    o[4] = (short)f2bu(b.x); o[5] = (short)f2bu(b.y);
    o[6] = (short)f2bu(b.z); o[7] = (short)f2bu(b.w);
    *(short8*)(Apk + (size_t)cid * 8) = o;
}

// W fp32 [K][N] row-major -> bf16 B-frag-packed [ntG][kg][n16][8]
__global__ __launch_bounds__(256)
void pack_w(const float* __restrict__ W, bf16* __restrict__ out, int K, int N)
{
    const int cid = blockIdx.x * 256 + threadIdx.x;
    const int KG = K >> 3;
    const int total = (N >> 4) * KG * 16;
    if (cid >= total) return;
    const int n = cid & 15;
    const int kg = (cid >> 4) % KG;
    const int ntG = (cid >> 4) / KG;
    short8 o;
#pragma unroll
    for (int j = 0; j < 8; ++j)
        o[j] = (short)f2bu(W[(size_t)(kg * 8 + j) * N + ntG * 16 + n]);
    *(short8*)(out + (size_t)cid * 8) = o;
}

__global__ __launch_bounds__(256)
void fuse_bias(const float* __restrict__ qb, const float* __restrict__ vb,
               float* __restrict__ out)
{
    const int t = blockIdx.x * 256 + threadIdx.x;
    if (t >= 576) return;
    out[t] = (t < 192) ? qb[t] : ((t < 384) ? 0.0f : vb[t - 384]);
}

// ---------------- MFMA GEMM ----------------
#define EPI_NONE 0
#define EPI_GELU 1

// A-frags in registers (packed layout == fragment layout).
// B staged async (global_load_lds) into double-buffered LDS; counted vmcnt
// waits + raw barriers keep prefetch + C-stores in flight across panels.
template<int KDIM, bool PACK_OUT, int EPI, int KGOUT, int MW>
__global__ __launch_bounds__(256, MW)
void gemm_mfma(const bf16* __restrict__ Apk, const bf16* __restrict__ Bpk,
               const float* __restrict__ bias, bf16* __restrict__ C, int N)
{
    constexpr int KG = KDIM / 8;     // k-groups of 8
    constexpr int KT = KDIM / 32;    // A-frags per 16-row tile
    constexpr int KC = KDIM / 192;   // 192-wide K chunks (stage granularity)
    __shared__ __align__(16) char sB[2][24576];
    const int tid = threadIdx.x;
    const int wave = tid >> 6, lane = tid & 63;
    const int bm = blockIdx.x * 128;
    const int NPo = N / 64;
    const char* Bsrc = (const char*)Bpk;

    // ---- A-frags -> registers, once per block ----
    short8 areg[2][KT];
    {
        const char* Asrc = (const char*)Apk;
#pragma unroll
        for (int x = 0; x < 2; ++x) {
            const size_t rowb = (size_t)((bm >> 4) + wave * 2 + x) * KG * 256;
#pragma unroll
            for (int kt = 0; kt < KT; ++kt)
                areg[x][kt] = *(const short8*)(Asrc + rowb + (size_t)kt * 1024 + lane * 16);
        }
    }

    // stage one 24 KB B panel (npo_, kc_) into sB[bufp] via async copy.
    // per (i,wave): dest chunk is contiguous 1 KiB, wave-uniform base.
    auto stage = [&](int npo_, int kc_, int bufp) {
#pragma unroll
        for (int i = 0; i < 6; ++i) {
            const int cid = i * 256 + wave * 64 + lane;
            const int nt = cid / 384, off = cid - nt * 384;
            const char* g = Bsrc + ((size_t)((npo_ * 4 + nt) * KG + kc_ * 24) * 256 + (size_t)off * 16);
            async_copy16(sB[bufp] + (i * 256 + wave * 64) * 16, g);
        }
    };

    stage(0, 0, 0);

    for (int npo = 0; npo < NPo; ++npo) {
        floatx4 acc[8];
#pragma unroll
        for (int f = 0; f < 8; ++f)
            acc[f] = (floatx4){0.f, 0.f, 0.f, 0.f};

#pragma unroll
        for (int kc = 0; kc < KC; ++kc) {
            const int p = npo * KC + kc;
            const int buf = p & 1;
            const bool last = (npo == NPo - 1) && (kc == KC - 1);
            if (!last) {
                if (kc < KC - 1) stage(npo, kc + 1, buf ^ 1);
                else             stage(npo + 1, 0, buf ^ 1);
                asm volatile("s_waitcnt vmcnt(6)" ::: "memory");   // buf ready; next stage stays in flight
            } else {
                asm volatile("s_waitcnt vmcnt(0)" ::: "memory");
            }
            __builtin_amdgcn_sched_barrier(0);
            asm volatile("s_barrier" ::: "memory");                // all waves' staging visible

            char* sb = sB[buf];
#pragma unroll
            for (int kt6 = 0; kt6 < 6; ++kt6) {
                const short8 a0 = areg[0][kc * 6 + kt6];
                const short8 a1 = areg[1][kc * 6 + kt6];
#pragma unroll
                for (int nt = 0; nt < 4; ++nt) {
                    const short8 b = *(const short8*)(sb + nt * 6144 + kt6 * 1024 + lane * 16);
                    acc[nt]     = __builtin_amdgcn_mfma_f32_16x16x32_bf16(a0, b, acc[nt],     0, 0, 0);
                    acc[4 + nt] = __builtin_amdgcn_mfma_f32_16x16x32_bf16(a1, b, acc[4 + nt], 0, 0, 0);
                }
            }
            if (kc < KC - 1)
                asm volatile("s_barrier" ::: "memory");            // free buf for next stage
        }

        // ---- epilogue: bias (+gelu), bf16, LDS transpose, coalesced store ----
        {
            const int ebuf = (npo * KC + KC - 1) & 1;
            asm volatile("s_barrier" ::: "memory");                // all waves done reading ebuf
            char* wb = sB[ebuf] + wave * 4608;
#pragma unroll
            for (int m2 = 0; m2 < 2; ++m2) {
#pragma unroll
                for (int nt = 0; nt < 4; ++nt) {
                    const floatx4 v = acc[m2 * 4 + nt];
                    const int c = nt * 16 + (lane & 15);
                    const float bval = bias ? bias[npo * 64 + c] : 0.0f;
#pragma unroll
                    for (int i = 0; i < 4; ++i) {
                        float f = v[i] + bval;
                        if (EPI == EPI_GELU)
                            f = gelu_fast(f);
                        const int r = m2 * 16 + (lane >> 4) * 4 + i;
                        *(unsigned short*)(wb + (r * 72 + c) * 2) = f2bu(f);
                    }
                }
            }
            asm volatile("s_waitcnt lgkmcnt(0)" ::: "memory");
            asm volatile("s_barrier" ::: "memory");                // wb visible
            if (PACK_OUT) {
                const int m = lane >> 1, c2 = (lane & 1) * 32;
                const int grow = bm + wave * 32 + m;
#pragma unroll
                for (int i = 0; i < 4; ++i) {
                    const short8 row = *(const short8*)(wb + (m * 72 + c2 + i * 8) * 2);
                    const int gcol = npo * 64 + c2 + i * 8;
                    bf16* dst = C + ((size_t)((grow >> 4) * KGOUT + (gcol >> 3)) * 16 + (grow & 15)) * 8;
                    *(short8*)dst = row;
                }
            } else {
                // full-128B-line stores: 8 lanes cover one row segment per issue
                const int mr = lane >> 3, c2 = (lane & 7) * 8;
#pragma unroll
                for (int i = 0; i < 4; ++i) {
                    const int rr = i * 8 + mr;
                    const short8 row = *(const short8*)(wb + (rr * 72 + c2) * 2);
                    bf16* dst = C + (size_t)(bm + wave * 32 + rr) * N + npo * 64 + c2;
                    *(short8*)dst = row;
                }
            }
            asm volatile("s_barrier" ::: "memory");                // wb region reusable
        }
    }
}

// ---------------- CPB MLP + RPB ----------------

__device__ __forceinline__ float cpb_coord(int i) {
    float a = (float)(i - 7) * (8.0f / 7.0f);
    float s = (a > 0.f) ? 1.f : ((a < 0.f) ? -1.f : 0.f);
    return s * log2f(fabsf(a) + 1.0f) * (1.0f / 3.0f);
}

__global__ __launch_bounds__(512)
void cpb_mlp(const float* __restrict__ w1, const float* __restrict__ b1,
             const float* __restrict__ w2, float* __restrict__ tab)
{
    const int r = blockIdx.x;
    const int t = threadIdx.x;
    const float x0 = cpb_coord(r / 15);
    const float x1 = cpb_coord(r % 15);
    const float hgt = fmaxf(x0 * w1[t] + x1 * w1[512 + t] + b1[t], 0.0f);
    __shared__ float red[512];
    for (int n = 0; n < 6; ++n) {
        red[t] = hgt * w2[t * 6 + n];
        __syncthreads();
        for (int s = 256; s > 0; s >>= 1) {
            if (t < s) red[t] += red[t + s];
            __syncthreads();
        }
        if (t == 0) tab[r * 6 + n] = red[0];
        __syncthreads();
    }
}

__global__ __launch_bounds__(256)
void rpb_expand(const float* __restrict__ tab, float* __restrict__ rpb)
{
    const int idx = blockIdx.x * 256 + threadIdx.x;
    if (idx >= 6 * 4096) return;
    const int h = idx >> 12;
    const int t = (idx >> 6) & 63;
    const int j = idx & 63;
    const int pr = t >> 3, pc = t & 7, qr = j >> 3, qc = j & 7;
    const int ridx = (pr - qr + 7) * 15 + (pc - qc + 7);
    const float v = tab[ridx * 6 + h];
    rpb[idx] = 16.0f / (1.0f + expf(-v));
}

// ---------------- MFMA attention ----------------
// one wave per (window, head); 4 waves/block; all LDS wave-private (no barriers).
__global__ __launch_bounds__(256, 2)
void attn_mfma(const bf16* __restrict__ QKV, const float* __restrict__ rpb,
               const float* __restrict__ logit_scale, bf16* __restrict__ Ctx)
{
    __shared__ __align__(16) char lds[4][9216];
    const int wave = threadIdx.x >> 6, lane = threadIdx.x & 63;
    const int l15 = lane & 15, quad = lane >> 4;
    const int wh = blockIdx.x * 4 + wave;
    const int w = wh / 6, h = wh - w * 6;
    char* Pb = lds[wave];            // 64 rows x 36 bf16 (P halves, then ctx)
    char* Vt = lds[wave] + 4608;     // 32 rows x 72 bf16 (V transposed)

    const bf16* wbase = QKV + (size_t)w * 64 * 576;

    // ---- stage V^T: lane = token, writes its column (2 lanes/bank: free) ----
    {
        const bf16* vp = wbase + (size_t)lane * 576 + 384 + h * 32;
        const short8 v0 = *(const short8*)(vp);
        const short8 v1 = *(const short8*)(vp + 8);
        const short8 v2 = *(const short8*)(vp + 16);
        const short8 v3 = *(const short8*)(vp + 24);
#pragma unroll
        for (int j = 0; j < 8; ++j) {
            *(short*)(Vt + ((j     ) * 72 + lane) * 2) = v0[j];
            *(short*)(Vt + ((j +  8) * 72 + lane) * 2) = v1[j];
            *(short*)(Vt + ((j + 16) * 72 + lane) * 2) = v2[j];
            *(short*)(Vt + ((j + 24) * 72 + lane) * 2) = v3[j];
        }
    }

    // ---- region ids (mask only matters on last window row/col) ----
    const int wr = w / 48, wc = w - wr * 48;
    const bool edge = (wr == 47) || (wc == 47);
    int rid_j[4];
    if (edge) {
#pragma unroll
        for (int jt = 0; jt < 4; ++jt) {
            const int t = jt * 16 + l15;
            const int rr = (wr == 47) ? (((t >> 3) < 4) ? 1 : 2) : 0;
            const int rc = (wc == 47) ? (((t & 7) < 4) ? 1 : 2) : 0;
            rid_j[jt] = rr * 3 + rc;
        }
    }

    // ---- K B-frags, cosine-normalized ----
    short8 bfrag[4];
#pragma unroll
    for (int jt = 0; jt < 4; ++jt) {
        const short8 raw = *(const short8*)(wbase + (size_t)(jt * 16 + l15) * 576 + 192 + h * 32 + quad * 8);
        float f[8]; float ss = 0.f;
#pragma unroll
        for (int j = 0; j < 8; ++j) { f[j] = bu2f((unsigned short)raw[j]); ss += f[j] * f[j]; }
        ss += __shfl_xor(ss, 16); ss += __shfl_xor(ss, 32);
        const float rn = 1.0f / fmaxf(sqrtf(ss), 1e-12f);
        short8 o;
#pragma unroll
        for (int j = 0; j < 8; ++j) o[j] = (short)f2bu(f[j] * rn);
        bfrag[jt] = o;
    }

    // ---- S = Qn Kn^T ----
    floatx4 acc[4][4];
#pragma unroll
    for (int it = 0; it < 4; ++it)
#pragma unroll
        for (int jt = 0; jt < 4; ++jt)
            acc[it][jt] = (floatx4){0.f, 0.f, 0.f, 0.f};
#pragma unroll
    for (int it = 0; it < 4; ++it) {
        const short8 raw = *(const short8*)(wbase + (size_t)(it * 16 + l15) * 576 + h * 32 + quad * 8);
        float f[8]; float ss = 0.f;
#pragma unroll
        for (int j = 0; j < 8; ++j) { f[j] = bu2f((unsigned short)raw[j]); ss += f[j] * f[j]; }
        ss += __shfl_xor(ss, 16); ss += __shfl_xor(ss, 32);
        const float rn = 1.0f / fmaxf(sqrtf(ss), 1e-12f);
        short8 afr;
#pragma unroll
        for (int j = 0; j < 8; ++j) afr[j] = (short)f2bu(f[j] * rn);
#pragma unroll
        for (int jt = 0; jt < 4; ++jt)
            acc[it][jt] = __builtin_amdgcn_mfma_f32_16x16x32_bf16(afr, bfrag[jt], acc[it][jt], 0, 0, 0);
    }

    const float scale = __expf(fminf(logit_scale[h], 4.6051701859880914f));
    const float* rpbh = rpb + h * 4096;

    // ---- scale + bias + mask (C-layout: row = it*16+quad*4+r, col = jt*16+l15) ----
#pragma unroll
    for (int it = 0; it < 4; ++it) {
#pragma unroll
        for (int r = 0; r < 4; ++r) {
            const int i = it * 16 + quad * 4 + r;
            int rid_i = 0;
            if (edge) {
                const int rr = (wr == 47) ? (((i >> 3) < 4) ? 1 : 2) : 0;
                const int rc = (wc == 47) ? (((i & 7) < 4) ? 1 : 2) : 0;
                rid_i = rr * 3 + rc;
            }
#pragma unroll
            for (int jt = 0; jt < 4; ++jt) {
                float v = acc[it][jt][r] * scale + rpbh[i * 64 + jt * 16 + l15];
                if (edge && rid_i != rid_j[jt]) v -= 200.0f;   // mask added twice in ref
                acc[it][jt][r] = v;
            }
        }
    }

    // ---- softmax per row; keep 1/sum for post-PV scaling ----
    float inv[4][4];
#pragma unroll
    for (int it = 0; it < 4; ++it) {
#pragma unroll
        for (int r = 0; r < 4; ++r) {
            float m = fmaxf(fmaxf(acc[it][0][r], acc[it][1][r]),
                            fmaxf(acc[it][2][r], acc[it][3][r]));
            m = fmaxf(m, __shfl_xor(m, 1)); m = fmaxf(m, __shfl_xor(m, 2));
            m = fmaxf(m, __shfl_xor(m, 4)); m = fmaxf(m, __shfl_xor(m, 8));
            float s = 0.f;
#pragma unroll
            for (int jt = 0; jt < 4; ++jt) {
                const float e = __expf(acc[it][jt][r] - m);
                acc[it][jt][r] = e; s += e;
            }
            s += __shfl_xor(s, 1); s += __shfl_xor(s, 2);
            s += __shfl_xor(s, 4); s += __shfl_xor(s, 8);
            inv[it][r] = 1.0f / s;
        }
    }

    // ---- ctx = P V via LDS round-trip in two 32-key halves ----
    floatx4 ctx[4][2];
#pragma unroll
    for (int it = 0; it < 4; ++it)
#pragma unroll
        for (int dt = 0; dt < 2; ++dt)
            ctx[it][dt] = (floatx4){0.f, 0.f, 0.f, 0.f};

#pragma unroll
    for (int ks = 0; ks < 2; ++ks) {
#pragma unroll
        for (int it = 0; it < 4; ++it)
#pragma unroll
            for (int jl = 0; jl < 2; ++jl)
#pragma unroll
                for (int r = 0; r < 4; ++r) {
                    const int i = it * 16 + quad * 4 + r;
                    *(short*)(Pb + (i * 36 + jl * 16 + l15) * 2) =
                        (short)f2bu(acc[it][ks * 2 + jl][r]);
                }
#pragma unroll
        for (int it = 0; it < 4; ++it) {
            const short8 pf = *(const short8*)(Pb + ((it * 16 + l15) * 36 + quad * 8) * 2);
#pragma unroll
            for (int dt = 0; dt < 2; ++dt) {
                const short8 vf = *(const short8*)(Vt + ((dt * 16 + l15) * 72 + ks * 32 + quad * 8) * 2);
                ctx[it][dt] = __builtin_amdgcn_mfma_f32_16x16x32_bf16(pf, vf, ctx[it][dt], 0, 0, 0);
            }
        }
    }

    // ---- ctx/sum -> LDS (reuse Pb; same-wave order keeps it race-free) ----
#pragma unroll
    for (int it = 0; it < 4; ++it)
#pragma unroll
        for (int dt = 0; dt < 2; ++dt)
#pragma unroll
            for (int r = 0; r < 4; ++r) {
                const int i = it * 16 + quad * 4 + r;
                *(short*)(Pb + (i * 36 + dt * 16 + l15) * 2) =
                    (short)f2bu(ctx[it][dt][r] * inv[it][r]);
            }

    // ---- packed-A-layout store for proj GEMM ----
    const int tok = w * 64 + lane;
    const size_t obase = ((size_t)(tok >> 4) * 24 + h * 4) * 128 + (size_t)(tok & 15) * 8;
#pragma unroll
    for (int c = 0; c < 4; ++c) {
        const short8 row = *(const short8*)(Pb + (lane * 36 + c * 8) * 2);
        *(short8*)(Ctx + obase + (size_t)c * 128) = row;
    }
}

// ---------------- LN kernels ----------------

__global__ __launch_bounds__(256)
void ln_h(const bf16* __restrict__ X, const float* __restrict__ hidden,
          const float* __restrict__ g, const float* __restrict__ b,
          bf16* __restrict__ Hres, bf16* __restrict__ Hpk)
{
    const int lane = threadIdx.x & 63;
    const int wv = threadIdx.x >> 6;
    const int tok = blockIdx.x * 4 + wv;
    const int grow = gather_row(tok);
    __shared__ float rows[4][192];
    const bf16* xr = X + (size_t)tok * 192;
    const float x0 = bu2f(*(const unsigned short*)(xr + lane));
    const float x1 = bu2f(*(const unsigned short*)(xr + lane + 64));
    const float x2 = bu2f(*(const unsigned short*)(xr + lane + 128));
    float s = x0 + x1 + x2;
#pragma unroll
    for (int o = 32; o > 0; o >>= 1) s += __shfl_xor(s, o);
    const float mean = s * (1.0f / 192.0f);
    const float d0 = x0 - mean, d1 = x1 - mean, d2 = x2 - mean;
    float vsum = d0 * d0 + d1 * d1 + d2 * d2;
#pragma unroll
    for (int o = 32; o > 0; o >>= 1) vsum += __shfl_xor(vsum, o);
    const float rstd = rsqrtf(vsum * (1.0f / 192.0f) + 1e-5f);
    const float* hr = hidden + (size_t)grow * 192;
    const float h0 = hr[lane]       + d0 * rstd * g[lane]       + b[lane];
    const float h1 = hr[lane + 64]  + d1 * rstd * g[lane + 64]  + b[lane + 64];
    const float h2 = hr[lane + 128] + d2 * rstd * g[lane + 128] + b[lane + 128];
    bf16* hres = Hres + (size_t)tok * 192;
    *(unsigned short*)(hres + lane)       = f2bu(h0);
    *(unsigned short*)(hres + lane + 64)  = f2bu(h1);
    *(unsigned short*)(hres + lane + 128) = f2bu(h2);
    rows[wv][lane] = h0; rows[wv][lane + 64] = h1; rows[wv][lane + 128] = h2;
    __syncthreads();
    if (lane < 24) {
        short8 o;
#pragma unroll
        for (int j = 0; j < 8; ++j) o[j] = (short)f2bu(rows[wv][lane * 8 + j]);
        const int mtG = tok >> 4, mm = tok & 15;
        *(short8*)(Hpk + ((size_t)(mtG * 24 + lane) * 16 + mm) * 8) = o;
    }
}

__global__ __launch_bounds__(256)
void ln_out(const bf16* __restrict__ Y, const bf16* __restrict__ Hres,
            const float* __restrict__ g, const float* __restrict__ b,
            float* __restrict__ Out)
{
    const int lane = threadIdx.x & 63;
    const int tok = blockIdx.x * 4 + (threadIdx.x >> 6);
    const int grow = gather_row(tok);
    const bf16* yr = Y + (size_t)tok * 192;
    const float x0 = bu2f(*(const unsigned short*)(yr + lane));
    const float x1 = bu2f(*(const unsigned short*)(yr + lane + 64));
    const float x2 = bu2f(*(const unsigned short*)(yr + lane + 128));
    float s = x0 + x1 + x2;
#pragma unroll
    for (int o = 32; o > 0; o >>= 1) s += __shfl_xor(s, o);
    const float mean = s * (1.0f / 192.0f);
    const float d0 = x0 - mean, d1 = x1 - mean, d2 = x2 - mean;
    float vsum = d0 * d0 + d1 * d1 + d2 * d2;
#pragma unroll
    for (int o = 32; o > 0; o >>= 1) vsum += __shfl_xor(vsum, o);
    const float rstd = rsqrtf(vsum * (1.0f / 192.0f) + 1e-5f);
    const bf16* hr = Hres + (size_t)tok * 192;
    float* op = Out + (size_t)grow * 192;
    op[lane]       = bu2f(*(const unsigned short*)(hr + lane))       + d0 * rstd * g[lane]       + b[lane];
    op[lane + 64]  = bu2f(*(const unsigned short*)(hr + lane + 64))  + d1 * rstd * g[lane + 64]  + b[lane + 64];
    op[lane + 128] = bu2f(*(const unsigned short*)(hr + lane + 128)) + d2 * rstd * g[lane + 128] + b[lane + 128];
}

// ---------------- launch ----------------

extern "C" void kernel_launch(void* const* d_in, const int* in_sizes, int n_in,
                              void* d_out, int out_size, void* d_ws, size_t ws_size,
                              hipStream_t stream)
{
    const float* hidden = (const float*)d_in[0];
    const float* q_w = (const float*)d_in[1];
    const float* q_b = (const float*)d_in[2];
    const float* k_w = (const float*)d_in[3];
    const float* v_w = (const float*)d_in[4];
    const float* v_b = (const float*)d_in[5];
    const float* logit_scale = (const float*)d_in[6];
    const float* cpb_w1 = (const float*)d_in[7];
    const float* cpb_b1 = (const float*)d_in[8];
    const float* cpb_w2 = (const float*)d_in[9];
    const float* proj_w = (const float*)d_in[10];
    const float* proj_b = (const float*)d_in[11];
    const float* ln1_g = (const float*)d_in[12];
    const float* ln1_b = (const float*)d_in[13];
    const float* fc1_w = (const float*)d_in[14];
    const float* fc1_b = (const float*)d_in[15];
    const float* fc2_w = (const float*)d_in[16];
    const float* fc2_b = (const float*)d_in[17];
    const float* ln2_g = (const float*)d_in[18];
    const float* ln2_b = (const float*)d_in[19];

    char* ws = (char*)d_ws;
    bf16*  APK   = (bf16*)(ws + 0);
    float* RPB   = (float*)(ws + 0);
    bf16*  PROJW = (bf16*)(ws + (1 << 20));
    bf16*  MID   = (bf16*)(ws + 0);
    bf16*  CTX   = (bf16*)(ws + 56623104);
    bf16*  QKVW  = (bf16*)(ws + 56623104);
    float* QKVB  = (float*)(ws + 56844288);
    float* TAB   = (float*)(ws + 56846592);
    bf16*  QKV   = (bf16*)(ws + 113246208);
    bf16*  HRES  = (bf16*)(ws + 113246208);
    bf16*  HPK   = (bf16*)(ws + 169869312);
    bf16*  Y     = (bf16*)(ws + 226492416);
    bf16*  X     = (bf16*)(ws + 283115520);
    bf16*  FC1W  = (bf16*)(ws + 283115520);
    bf16*  FC2W  = (bf16*)(ws + 283262976);
    float* OUT   = (float*)d_out;

    cpb_mlp<<<225, 512, 0, stream>>>(cpb_w1, cpb_b1, cpb_w2, TAB);
    fuse_bias<<<3, 256, 0, stream>>>(q_b, v_b, QKVB);
    pack_w<<<18, 256, 0, stream>>>(q_w, QKVW,                 192, 192);
    pack_w<<<18, 256, 0, stream>>>(k_w, QKVW + 12 * 24 * 128, 192, 192);
    pack_w<<<18, 256, 0, stream>>>(v_w, QKVW + 24 * 24 * 128, 192, 192);
    conv_pack<<<13824, 256, 0, stream>>>(hidden, APK);

    gemm_mfma<192, false, EPI_NONE, 1, 3><<<1152, 256, 0, stream>>>(APK, QKVW, QKVB, QKV, 576);

    rpb_expand<<<96, 256, 0, stream>>>(TAB, RPB);
    pack_w<<<18, 256, 0, stream>>>(proj_w, PROJW, 192, 192);

    attn_mfma<<<3456, 256, 0, stream>>>(QKV, RPB, logit_scale, CTX);

    gemm_mfma<192, false, EPI_NONE, 1, 3><<<1152, 256, 0, stream>>>(CTX, PROJW, proj_b, X, 192);

    ln_h<<<NTOK / 4, 256, 0, stream>>>(X, hidden, ln1_g, ln1_b, HRES, HPK);

    pack_w<<<36, 256, 0, stream>>>(fc1_w, FC1W, 192, 384);
    pack_w<<<36, 256, 0, stream>>>(fc2_w, FC2W, 384, 192);

    gemm_mfma<192, true, EPI_GELU, 48, 3><<<1152, 256, 0, stream>>>(HPK, FC1W, fc1_b, MID, 384);
    gemm_mfma<384, false, EPI_NONE, 1, 2><<<1152, 256, 0, stream>>>(MID, FC2W, fc2_b, Y, 192);

    ln_out<<<NTOK / 4, 256, 0, stream>>>(Y, HRES, ln2_g, ln2_b, OUT);
}